// Round 2
// baseline (294.165 us; speedup 1.0000x reference)
//
#include <hip/hip_runtime.h>

#define N_NODES 100000
#define N_EDGES 1600000
#define D 128
#define NB 782    // buckets of 128 rows
#define BCAP 2560 // per-bucket capacity: mean 2046, sigma 45 -> +11 sigma

typedef unsigned short u16;
typedef unsigned int u32;
typedef __attribute__((ext_vector_type(8))) short bf16x8;
typedef __attribute__((ext_vector_type(4))) float f32x4;

__device__ __forceinline__ u16 f2bf(float f) {
    u32 u = __float_as_uint(f);
    u += 0x7fffu + ((u >> 16) & 1u);  // round-to-nearest-even
    return (u16)(u >> 16);
}

// ---------------- fused front end: bin_pass | convert_feat | convert_w ----------------
// Bin blocks FIRST: they are the latency-bound critical path (atomics + scattered
// 8B writes); launching them at t=0 lets the 6378 streaming convert blocks backfill
// CUs while bins drain (prev version ran 391 bin blocks alone at 16% occupancy).
// Bin granularity 4x finer (1024 edges/block, 1563 blocks -> ~6 blocks/CU) for
// latency hiding; per-block NB-histogram overhead stays ~10 loop iterations.

#define BIN_BLKS 1563  // ceil(E/1024)
#define CF_BLKS 6250   // N*D/8/256
#define CW_BLKS 128    // 32768/256

__global__ __launch_bounds__(256) void prep(
    const float* __restrict__ features, u32* __restrict__ featb,
    const float* __restrict__ W1, const float* __restrict__ W2,
    u16* __restrict__ W1t, u16* __restrict__ W2t,
    const int* __restrict__ row, const int* __restrict__ col,
    const float* __restrict__ val,
    int* __restrict__ bucketCount, int2* __restrict__ binned) {
    __shared__ int hist[NB];
    __shared__ int lbase[NB];
    int bid = blockIdx.x;
    int t = threadIdx.x;

    if (bid >= BIN_BLKS) {
        int cid = bid - BIN_BLKS;
        if (cid < CF_BLKS) {
            // features fp32 [N,128] -> bf16 packed (word j = cols {2j,2j+1})
            int idx = cid * 256 + t;  // [0, N*D/8)
            const float4* f4 = (const float4*)features;
            float4 a = f4[idx * 2], b = f4[idx * 2 + 1];
            uint4 o;
            o.x = (u32)f2bf(a.x) | ((u32)f2bf(a.y) << 16);
            o.y = (u32)f2bf(a.z) | ((u32)f2bf(a.w) << 16);
            o.z = (u32)f2bf(b.x) | ((u32)f2bf(b.y) << 16);
            o.w = (u32)f2bf(b.z) | ((u32)f2bf(b.w) << 16);
            ((uint4*)featb)[idx] = o;
        } else {
            // W[k][n] fp32 -> Wt[n][k] bf16, both 128x128
            int flat = (cid - CF_BLKS) * 256 + t;  // [0, 32768)
            int m = flat >> 14;
            int idx = flat & 16383;
            int n = idx & 127;
            int k = idx >> 7;
            const float* src = m ? W2 : W1;
            u16* dst = m ? W2t : W1t;
            dst[n * 128 + k] = f2bf(src[k * 128 + n]);
        }
        return;
    }

    // bin_pass: append edges into fixed-capacity buckets; pack row-local (7b)
    // into col's high bits
    int b = bid;
    for (int i = t; i < NB; i += 256) hist[i] = 0;
    __syncthreads();
    int base = b * 1024;
    int r[4];
#pragma unroll
    for (int i = 0; i < 4; ++i) {
        int e = base + i * 256 + t;
        r[i] = (e < N_EDGES) ? row[e] : -1;
        if (r[i] >= 0) atomicAdd(&hist[r[i] >> 7], 1);
    }
    __syncthreads();
    for (int i = t; i < NB; i += 256) {
        int c = hist[i];
        lbase[i] = c ? atomicAdd(&bucketCount[i], c) : 0;
    }
    __syncthreads();
    for (int i = t; i < NB; i += 256) hist[i] = 0;  // reuse as local cursor
    __syncthreads();
#pragma unroll
    for (int i = 0; i < 4; ++i) {
        if (r[i] < 0) continue;
        int e = base + i * 256 + t;
        int bkt = r[i] >> 7;
        int pos = bkt * BCAP + lbase[bkt] + atomicAdd(&hist[bkt], 1);
        int2 ev;
        ev.x = col[e] | ((r[i] & 127) << 17);  // col < 2^17
        ev.y = __float_as_int(val[e]);
        binned[pos] = ev;
    }
}

// one block per bucket: per-row counts -> rowRange (beg,end), scatter into
// row-sorted scev. Bucket data (<=2560 int2 = 20.5KB) is staged in LDS during
// the histogram pass so the scatter pass reads LDS instead of re-reading 12.8MB
// from global. All scev writes land in the bucket's own ~20KB window.
__global__ __launch_bounds__(256) void bucket_sort(const int2* __restrict__ binned,
                                                   const int* __restrict__ bucketCount,
                                                   int2* __restrict__ rowRange,
                                                   int2* __restrict__ scev) {
    __shared__ int h[128];
    __shared__ int cur[128];
    __shared__ int2 evs[BCAP];
    int b = blockIdx.x, t = threadIdx.x;
    int row0 = b << 7;
    int nrows = N_NODES - row0;
    if (nrows > 128) nrows = 128;
    if (t < 128) h[t] = 0;
    __syncthreads();
    int lo = b * BCAP;
    int cnt = bucketCount[b];
    for (int i = t; i < cnt; i += 256) {
        int2 ev = binned[lo + i];
        evs[i] = ev;
        atomicAdd(&h[((u32)ev.x) >> 17], 1);
    }
    __syncthreads();
    if (t < 128) cur[t] = h[t];
    __syncthreads();
    for (int d = 1; d < 128; d <<= 1) {
        int x = 0;
        if (t < 128 && t >= d) x = cur[t - d];
        __syncthreads();
        if (t < 128) cur[t] += x;
        __syncthreads();
    }
    if (t < 128) {
        int excl = lo + cur[t] - h[t];
        if (t < nrows) rowRange[row0 + t] = make_int2(excl, excl + h[t]);
        cur[t] = excl;  // per-row cursor
    }
    __syncthreads();
    for (int i = t; i < cnt; i += 256) {
        int2 ev = evs[i];
        int rl = ((u32)ev.x) >> 17;
        int pos = atomicAdd(&cur[rl], 1);
        scev[pos] = make_int2(ev.x & 0x1FFFF, ev.y);
    }
}

// ---------------- SpMM (bf16 gather): one wave per row ----------------
// Xb[r] = bf16( featb[r] + sum_j v_j * featb[col_j] )
// wid wave-uniform via readfirstlane -> rowRange/scev become scalar loads.
// Single clamped 16-deep batch loop: ALWAYS issue 16 gathers, clamping the
// index to end-1 and zeroing the value for inactive slots. Duplicate gathers
// hit the just-fetched line in L1/L2 (no extra HBM fetch); every row becomes
// ceil(deg/16) full-MLP batches instead of draining a ~7.5-edge tail.

__global__ __launch_bounds__(256) void spmm_bf16(
    const int2* __restrict__ scev, const int2* __restrict__ rowRange,
    const u32* __restrict__ featb, u32* __restrict__ Xb) {
    int wid0 = (blockIdx.x * blockDim.x + threadIdx.x) >> 6;
    int wid = __builtin_amdgcn_readfirstlane(wid0);
    int lane = threadIdx.x & 63;
    if (wid >= N_NODES) return;
    int2 rr = rowRange[wid];
    int j = rr.x, end = rr.y;
    u32 self = featb[wid * 64 + lane];
    float ax0 = __uint_as_float(self << 16);
    float ay0 = __uint_as_float(self & 0xffff0000u);
    float ax1 = 0.f, ay1 = 0.f;
    for (; j < end; j += 16) {
        int2 e[16];
        u32 p[16];
#pragma unroll
        for (int u = 0; u < 16; ++u) {
            int idx = j + u;
            int c = (idx < end) ? idx : (end - 1);  // uniform: stays scalar
            e[u] = scev[c];
            if (idx >= end) e[u].y = 0;  // inactive slot contributes 0
        }
#pragma unroll
        for (int u = 0; u < 16; ++u) p[u] = featb[e[u].x * 64 + lane];
#pragma unroll
        for (int u = 0; u < 16; ++u) {
            float v = __int_as_float(e[u].y);
            float lo = __uint_as_float(p[u] << 16);
            float hi = __uint_as_float(p[u] & 0xffff0000u);
            if (u & 1) {
                ax1 += v * lo;
                ay1 += v * hi;
            } else {
                ax0 += v * lo;
                ay0 += v * hi;
            }
        }
    }
    float accx = ax0 + ax1;
    float accy = ay0 + ay1;
    Xb[wid * 64 + lane] = (u32)f2bf(accx) | ((u32)f2bf(accy) << 16);
}

// ---------------- fused MFMA GEMM: out = relu(X@W1+b1)@W2 + b2 ----------------
// Stage 1: W1 staged in LDS, MFMA -> bias+ReLU. H never touches HBM:
// C-fragments packed as bf16 u32-pairs into a TRANSPOSED LDS tile Ht[col][row]
// aliased over Ws (W1 dead after stage 1; barrier-separated). Stage-2
// A-fragments read Ht[k][l16] conflict-free; B-fragments stream straight from
// global W2t (32 KB, L2-resident). Saves the 51.2 MB Hb round-trip + a launch.

__global__ __launch_bounds__(256, 2) void gemm_fused(
    const u16* __restrict__ Xb, const u16* __restrict__ W1t,
    const float* __restrict__ b1, const u16* __restrict__ W2t,
    const float* __restrict__ b2, float* __restrict__ outf) {
    __shared__ u16 Ws[128][136];            // 34816 B; stage 2 aliases Ht over it
    u16(*Ht)[130] = (u16(*)[130]) & Ws[0][0];  // 128x130 = 33280 B <= 34816

    int t = threadIdx.x;
    {
        const uint4* wsrc = (const uint4*)W1t;
#pragma unroll
        for (int i = 0; i < 8; ++i) {
            int f = t + 256 * i;
            *(uint4*)&Ws[f >> 4][(f & 15) << 3] = wsrc[f];
        }
    }
    __syncthreads();

    int w = t >> 6, lane = t & 63;
    int quad = lane >> 4, l16 = lane & 15;
    int row0 = blockIdx.x * 128 + w * 32;

    f32x4 acc[2][8];
#pragma unroll
    for (int rt = 0; rt < 2; ++rt)
#pragma unroll
        for (int ct = 0; ct < 8; ++ct) acc[rt][ct] = (f32x4){0.f, 0.f, 0.f, 0.f};

    int ra = row0 + l16;
    int rb = row0 + 16 + l16;
    if (ra > N_NODES - 1) ra = N_NODES - 1;
    if (rb > N_NODES - 1) rb = N_NODES - 1;
    const u16* pa = Xb + (size_t)ra * D + quad * 8;
    const u16* pb = Xb + (size_t)rb * D + quad * 8;

#pragma unroll
    for (int kb = 0; kb < 128; kb += 32) {
        bf16x8 a0 = *(const bf16x8*)(pa + kb);
        bf16x8 a1 = *(const bf16x8*)(pb + kb);
#pragma unroll
        for (int ct = 0; ct < 8; ++ct) {
            bf16x8 b = *(const bf16x8*)&Ws[ct * 16 + l16][kb + quad * 8];
            acc[0][ct] = __builtin_amdgcn_mfma_f32_16x16x32_bf16(a0, b, acc[0][ct], 0, 0, 0);
            acc[1][ct] = __builtin_amdgcn_mfma_f32_16x16x32_bf16(a1, b, acc[1][ct], 0, 0, 0);
        }
    }

    float bv1[8];
#pragma unroll
    for (int ct = 0; ct < 8; ++ct) bv1[ct] = b1[ct * 16 + l16];

    __syncthreads();  // all W1 reads complete before Ht overwrites Ws

    int hbase = w * 32;  // this wave's local row base
#pragma unroll
    for (int rt = 0; rt < 2; ++rt) {
#pragma unroll
        for (int ct = 0; ct < 8; ++ct) {
            float v0 = fmaxf(acc[rt][ct][0] + bv1[ct], 0.f);
            float v1 = fmaxf(acc[rt][ct][1] + bv1[ct], 0.f);
            float v2 = fmaxf(acc[rt][ct][2] + bv1[ct], 0.f);
            float v3 = fmaxf(acc[rt][ct][3] + bv1[ct], 0.f);
            u16* dst = &Ht[ct * 16 + l16][hbase + rt * 16 + quad * 4];
            ((u32*)dst)[0] = (u32)f2bf(v0) | ((u32)f2bf(v1) << 16);
            ((u32*)dst)[1] = (u32)f2bf(v2) | ((u32)f2bf(v3) << 16);
        }
    }
    __syncthreads();

    f32x4 acc2[2][8];
#pragma unroll
    for (int rt = 0; rt < 2; ++rt)
#pragma unroll
        for (int ct = 0; ct < 8; ++ct) acc2[rt][ct] = (f32x4){0.f, 0.f, 0.f, 0.f};

#pragma unroll
    for (int kb = 0; kb < 128; kb += 32) {
        bf16x8 a0, a1;
#pragma unroll
        for (int i = 0; i < 8; ++i) {
            a0[i] = (short)Ht[kb + quad * 8 + i][hbase + l16];
            a1[i] = (short)Ht[kb + quad * 8 + i][hbase + 16 + l16];
        }
#pragma unroll
        for (int ct = 0; ct < 8; ++ct) {
            bf16x8 b = *(const bf16x8*)(W2t + (size_t)(ct * 16 + l16) * D + kb + quad * 8);
            acc2[0][ct] = __builtin_amdgcn_mfma_f32_16x16x32_bf16(a0, b, acc2[0][ct], 0, 0, 0);
            acc2[1][ct] = __builtin_amdgcn_mfma_f32_16x16x32_bf16(a1, b, acc2[1][ct], 0, 0, 0);
        }
    }

    float bv2[8];
#pragma unroll
    for (int ct = 0; ct < 8; ++ct) bv2[ct] = b2[ct * 16 + l16];

#pragma unroll
    for (int rt = 0; rt < 2; ++rt) {
#pragma unroll
        for (int r = 0; r < 4; ++r) {
            int row = row0 + rt * 16 + quad * 4 + r;
            if (row >= N_NODES) continue;
#pragma unroll
            for (int ct = 0; ct < 8; ++ct) {
                outf[(size_t)row * D + ct * 16 + l16] = acc2[rt][ct][r] + bv2[ct];
            }
        }
    }
}

extern "C" void kernel_launch(void* const* d_in, const int* in_sizes, int n_in,
                              void* d_out, int out_size, void* d_ws, size_t ws_size,
                              hipStream_t stream) {
    const int* indices = (const int*)d_in[0];      // [2, E]
    const float* values = (const float*)d_in[1];   // [E]
    const float* features = (const float*)d_in[2]; // [N, 128]
    const float* W1 = (const float*)d_in[3];
    const float* b1 = (const float*)d_in[4];
    const float* W2 = (const float*)d_in[5];
    const float* b2 = (const float*)d_in[6];

    const int* row = indices;
    const int* col = indices + N_EDGES;

    // ws (ints): bucketCount[NB] pad | rowRange[N] int2 | scev[NB*BCAP] int2 |
    //            Xb[N*64] u32 | W1t/W2t u16      total ~42.5 MB
    int* wsI = (int*)d_ws;
    int* bucketCount = wsI;                          // @0, NB ints (pad to 784)
    int2* rowRange = (int2*)(wsI + 784);             // 800 KB
    int2* scev = (int2*)(wsI + 784 + 2 * N_NODES);   // 16.0 MB
    u32* Xb = (u32*)(wsI + 784 + 2 * N_NODES + 2 * NB * BCAP);  // 25.6 MB, 16B-aligned
    u16* W1t = (u16*)(Xb + (size_t)N_NODES * 64);
    u16* W2t = W1t + 16384;

    // d_out: binned[NB*BCAP] int2 (16.0 MB, dead after bucket_sort) lower part;
    // featb (bf16 features, 25.6 MB, dead after spmm) upper half;
    // gemm_fused overwrites everything with outf.
    int2* binned = (int2*)d_out;
    u32* featb = (u32*)((char*)d_out + (size_t)N_NODES * D * 2);
    float* outf = (float*)d_out;

    hipMemsetAsync(bucketCount, 0, NB * sizeof(int), stream);

    prep<<<BIN_BLKS + CF_BLKS + CW_BLKS, 256, 0, stream>>>(
        features, featb, W1, W2, W1t, W2t, row, col, values, bucketCount, binned);

    bucket_sort<<<NB, 256, 0, stream>>>(binned, bucketCount, rowRange, scev);

    spmm_bf16<<<(N_NODES * 64 + 255) / 256, 256, 0, stream>>>(scev, rowRange, featb, Xb);

    gemm_fused<<<(N_NODES + 127) / 128, 256, 0, stream>>>(
        (const u16*)Xb, W1t, b1, W2t, b2, outf);
}

// Round 3
// 252.698 us; speedup vs baseline: 1.1641x; 1.1641x over previous
//
#include <hip/hip_runtime.h>

#define N_NODES 100000
#define N_EDGES 1600000
#define D 128
#define CB 98       // coarse buckets of 1024 rows (ceil(100000/1024))
#define CCAP 17920  // per-bucket capacity: mean 16384, sigma 128 -> +12 sigma

typedef unsigned short u16;
typedef unsigned int u32;
typedef __attribute__((ext_vector_type(8))) short bf16x8;
typedef __attribute__((ext_vector_type(4))) float f32x4;

__device__ __forceinline__ u16 f2bf(float f) {
    u32 u = __float_as_uint(f);
    u += 0x7fffu + ((u >> 16) & 1u);  // round-to-nearest-even
    return (u16)(u >> 16);
}

// ---------------- fused front end: bin_pass | convert_feat | convert_w ----------------
// Coarse binning: 98 buckets x 1024 rows. Per 4096-edge block: LDS hist over 98
// counters, ONE returning device atomic per (block,bucket) = 38K total (was 890K
// into 49 lines -> serialization). coarseCount padded to 1 counter/cacheline.
// Scatter: ~42 consecutive edges per bucket per block (~340B runs) -> near-full-
// line writes, kills the 4x RMW write amplification seen in round 1 (WRITE_SIZE 80MB).

#define BIN_BLKS 391  // ceil(E/4096)
#define CF_BLKS 6250  // N*D/8/256
#define CW_BLKS 128   // 32768/256

__global__ __launch_bounds__(256) void prep(
    const float* __restrict__ features, u32* __restrict__ featb,
    const float* __restrict__ W1, const float* __restrict__ W2,
    u16* __restrict__ W1t, u16* __restrict__ W2t,
    const int* __restrict__ row, const int* __restrict__ col,
    const float* __restrict__ val,
    int* __restrict__ coarseCount, int2* __restrict__ binned) {
    __shared__ int h[CB];
    __shared__ int lb[CB];
    int bid = blockIdx.x;
    int t = threadIdx.x;

    if (bid >= BIN_BLKS) {
        int cid = bid - BIN_BLKS;
        if (cid < CF_BLKS) {
            // features fp32 [N,128] -> bf16 packed (word j = cols {2j,2j+1})
            int idx = cid * 256 + t;  // [0, N*D/8)
            const float4* f4 = (const float4*)features;
            float4 a = f4[idx * 2], b = f4[idx * 2 + 1];
            uint4 o;
            o.x = (u32)f2bf(a.x) | ((u32)f2bf(a.y) << 16);
            o.y = (u32)f2bf(a.z) | ((u32)f2bf(a.w) << 16);
            o.z = (u32)f2bf(b.x) | ((u32)f2bf(b.y) << 16);
            o.w = (u32)f2bf(b.z) | ((u32)f2bf(b.w) << 16);
            ((uint4*)featb)[idx] = o;
        } else {
            // W[k][n] fp32 -> Wt[n][k] bf16, both 128x128
            int flat = (cid - CF_BLKS) * 256 + t;  // [0, 32768)
            int m = flat >> 14;
            int idx = flat & 16383;
            int n = idx & 127;
            int k = idx >> 7;
            const float* src = m ? W2 : W1;
            u16* dst = m ? W2t : W1t;
            dst[n * 128 + k] = f2bf(src[k * 128 + n]);
        }
        return;
    }

    // bin_pass: append edges into coarse buckets; pack row-local (10b) into
    // col's high bits (col < 2^17)
    if (t < CB) h[t] = 0;
    __syncthreads();
    int base = bid * 4096;
    int r[16];
#pragma unroll
    for (int i = 0; i < 16; ++i) {
        int e = base + i * 256 + t;
        r[i] = (e < N_EDGES) ? row[e] : -1;
        if (r[i] >= 0) atomicAdd(&h[r[i] >> 10], 1);
    }
    __syncthreads();
    if (t < CB) {
        int c = h[t];
        lb[t] = c ? atomicAdd(&coarseCount[t * 16], c) : 0;  // padded: 1/line
        h[t] = 0;                                            // reuse as cursor
    }
    __syncthreads();
#pragma unroll
    for (int i = 0; i < 16; ++i) {
        if (r[i] < 0) continue;
        int e = base + i * 256 + t;
        int cb = r[i] >> 10;
        int pos = cb * CCAP + lb[cb] + atomicAdd(&h[cb], 1);
        int2 ev;
        ev.x = col[e] | ((r[i] & 1023) << 17);
        ev.y = __float_as_int(val[e]);
        binned[pos] = ev;
    }
}

// ---------------- sortk: one 1024-thread block per coarse bucket ----------------
// LDS hist over 1024 row-locals -> shuffle-hierarchical exclusive scan (wave
// scan via shfl_up + 16-wave base scan; 3 barriers total) -> rowRange (absolute
// positions into the PADDED per-bucket scev window; no cross-bucket scan needed)
// -> scatter binned -> row-sorted scev within the bucket's own ~140KB window.

__global__ __launch_bounds__(1024) void sortk(const int2* __restrict__ binned,
                                              const int* __restrict__ coarseCount,
                                              int2* __restrict__ rowRange,
                                              int2* __restrict__ scev) {
    __shared__ int h[1024];
    __shared__ int cur[1024];
    __shared__ int wsum[16];
    __shared__ int wbase[16];
    int b = blockIdx.x, t = threadIdx.x;
    int lane = t & 63, wv = t >> 6;
    int row0 = b << 10;
    int lo = b * CCAP;
    int cnt = coarseCount[b * 16];

    h[t] = 0;
    __syncthreads();
    for (int i = t; i < cnt; i += 1024)
        atomicAdd(&h[((u32)binned[lo + i].x) >> 17], 1);
    __syncthreads();

    int c = h[t];
    int x = c;  // inclusive scan within wave
#pragma unroll
    for (int d = 1; d < 64; d <<= 1) {
        int y = __shfl_up(x, d);
        if (lane >= d) x += y;
    }
    if (lane == 63) wsum[wv] = x;
    __syncthreads();
    if (t < 16) {
        int s = wsum[t], sx = s;
#pragma unroll
        for (int d = 1; d < 16; d <<= 1) {
            int y = __shfl_up(sx, d);
            if (lane >= d) sx += y;
        }
        wbase[t] = sx - s;  // exclusive base per wave
    }
    __syncthreads();
    int start = lo + wbase[wv] + (x - c);  // absolute exclusive prefix
    if (row0 + t < N_NODES) rowRange[row0 + t] = make_int2(start, start + c);
    cur[t] = start;
    __syncthreads();

    for (int i = t; i < cnt; i += 1024) {
        int2 ev = binned[lo + i];
        int rl = ((u32)ev.x) >> 17;
        int pos = atomicAdd(&cur[rl], 1);
        scev[pos] = make_int2(ev.x & 0x1FFFF, ev.y);
    }
}

// ---------------- SpMM (bf16 gather): one wave per row ----------------
// Xb[r] = bf16( featb[r] + sum_j v_j * featb[col_j] )
// wid wave-uniform via readfirstlane -> rowRange/scev become scalar loads.
// Single clamped 16-deep batch loop: ALWAYS issue 16 gathers, clamping the
// index to end-1 and zeroing the value for inactive slots. Duplicate gathers
// hit the just-fetched line in L1/L2; every row is ceil(deg/16) full batches.

__global__ __launch_bounds__(256) void spmm_bf16(
    const int2* __restrict__ scev, const int2* __restrict__ rowRange,
    const u32* __restrict__ featb, u32* __restrict__ Xb) {
    int wid0 = (blockIdx.x * blockDim.x + threadIdx.x) >> 6;
    int wid = __builtin_amdgcn_readfirstlane(wid0);
    int lane = threadIdx.x & 63;
    if (wid >= N_NODES) return;
    int2 rr = rowRange[wid];
    int j = rr.x, end = rr.y;
    u32 self = featb[wid * 64 + lane];
    float ax0 = __uint_as_float(self << 16);
    float ay0 = __uint_as_float(self & 0xffff0000u);
    float ax1 = 0.f, ay1 = 0.f;
    for (; j < end; j += 16) {
        int2 e[16];
        u32 p[16];
#pragma unroll
        for (int u = 0; u < 16; ++u) {
            int idx = j + u;
            int c = (idx < end) ? idx : (end - 1);  // uniform: stays scalar
            e[u] = scev[c];
            if (idx >= end) e[u].y = 0;  // inactive slot contributes 0
        }
#pragma unroll
        for (int u = 0; u < 16; ++u) p[u] = featb[e[u].x * 64 + lane];
#pragma unroll
        for (int u = 0; u < 16; ++u) {
            float v = __int_as_float(e[u].y);
            float lo = __uint_as_float(p[u] << 16);
            float hi = __uint_as_float(p[u] & 0xffff0000u);
            if (u & 1) {
                ax1 += v * lo;
                ay1 += v * hi;
            } else {
                ax0 += v * lo;
                ay0 += v * hi;
            }
        }
    }
    float accx = ax0 + ax1;
    float accy = ay0 + ay1;
    Xb[wid * 64 + lane] = (u32)f2bf(accx) | ((u32)f2bf(accy) << 16);
}

// ---------------- fused MFMA GEMM: out = relu(X@W1+b1)@W2 + b2 ----------------
// Stage 1: W1 staged in LDS, MFMA -> bias+ReLU. H never touches HBM:
// C-fragments packed as bf16 u32-pairs into a TRANSPOSED LDS tile Ht[col][row]
// aliased over Ws (W1 dead after stage 1; barrier-separated). Stage-2
// A-fragments read Ht[k][l16] conflict-free; B-fragments stream straight from
// global W2t (32 KB, L2-resident). Saves the 51.2 MB Hb round-trip + a launch.

__global__ __launch_bounds__(256, 2) void gemm_fused(
    const u16* __restrict__ Xb, const u16* __restrict__ W1t,
    const float* __restrict__ b1, const u16* __restrict__ W2t,
    const float* __restrict__ b2, float* __restrict__ outf) {
    __shared__ u16 Ws[128][136];               // 34816 B; stage 2 aliases Ht over it
    u16(*Ht)[130] = (u16(*)[130]) & Ws[0][0];  // 128x130 = 33280 B <= 34816

    int t = threadIdx.x;
    {
        const uint4* wsrc = (const uint4*)W1t;
#pragma unroll
        for (int i = 0; i < 8; ++i) {
            int f = t + 256 * i;
            *(uint4*)&Ws[f >> 4][(f & 15) << 3] = wsrc[f];
        }
    }
    __syncthreads();

    int w = t >> 6, lane = t & 63;
    int quad = lane >> 4, l16 = lane & 15;
    int row0 = blockIdx.x * 128 + w * 32;

    f32x4 acc[2][8];
#pragma unroll
    for (int rt = 0; rt < 2; ++rt)
#pragma unroll
        for (int ct = 0; ct < 8; ++ct) acc[rt][ct] = (f32x4){0.f, 0.f, 0.f, 0.f};

    int ra = row0 + l16;
    int rb = row0 + 16 + l16;
    if (ra > N_NODES - 1) ra = N_NODES - 1;
    if (rb > N_NODES - 1) rb = N_NODES - 1;
    const u16* pa = Xb + (size_t)ra * D + quad * 8;
    const u16* pb = Xb + (size_t)rb * D + quad * 8;

#pragma unroll
    for (int kb = 0; kb < 128; kb += 32) {
        bf16x8 a0 = *(const bf16x8*)(pa + kb);
        bf16x8 a1 = *(const bf16x8*)(pb + kb);
#pragma unroll
        for (int ct = 0; ct < 8; ++ct) {
            bf16x8 b = *(const bf16x8*)&Ws[ct * 16 + l16][kb + quad * 8];
            acc[0][ct] = __builtin_amdgcn_mfma_f32_16x16x32_bf16(a0, b, acc[0][ct], 0, 0, 0);
            acc[1][ct] = __builtin_amdgcn_mfma_f32_16x16x32_bf16(a1, b, acc[1][ct], 0, 0, 0);
        }
    }

    float bv1[8];
#pragma unroll
    for (int ct = 0; ct < 8; ++ct) bv1[ct] = b1[ct * 16 + l16];

    __syncthreads();  // all W1 reads complete before Ht overwrites Ws

    int hbase = w * 32;  // this wave's local row base
#pragma unroll
    for (int rt = 0; rt < 2; ++rt) {
#pragma unroll
        for (int ct = 0; ct < 8; ++ct) {
            float v0 = fmaxf(acc[rt][ct][0] + bv1[ct], 0.f);
            float v1 = fmaxf(acc[rt][ct][1] + bv1[ct], 0.f);
            float v2 = fmaxf(acc[rt][ct][2] + bv1[ct], 0.f);
            float v3 = fmaxf(acc[rt][ct][3] + bv1[ct], 0.f);
            u16* dst = &Ht[ct * 16 + l16][hbase + rt * 16 + quad * 4];
            ((u32*)dst)[0] = (u32)f2bf(v0) | ((u32)f2bf(v1) << 16);
            ((u32*)dst)[1] = (u32)f2bf(v2) | ((u32)f2bf(v3) << 16);
        }
    }
    __syncthreads();

    f32x4 acc2[2][8];
#pragma unroll
    for (int rt = 0; rt < 2; ++rt)
#pragma unroll
        for (int ct = 0; ct < 8; ++ct) acc2[rt][ct] = (f32x4){0.f, 0.f, 0.f, 0.f};

#pragma unroll
    for (int kb = 0; kb < 128; kb += 32) {
        bf16x8 a0, a1;
#pragma unroll
        for (int i = 0; i < 8; ++i) {
            a0[i] = (short)Ht[kb + quad * 8 + i][hbase + l16];
            a1[i] = (short)Ht[kb + quad * 8 + i][hbase + 16 + l16];
        }
#pragma unroll
        for (int ct = 0; ct < 8; ++ct) {
            bf16x8 b = *(const bf16x8*)(W2t + (size_t)(ct * 16 + l16) * D + kb + quad * 8);
            acc2[0][ct] = __builtin_amdgcn_mfma_f32_16x16x32_bf16(a0, b, acc2[0][ct], 0, 0, 0);
            acc2[1][ct] = __builtin_amdgcn_mfma_f32_16x16x32_bf16(a1, b, acc2[1][ct], 0, 0, 0);
        }
    }

    float bv2[8];
#pragma unroll
    for (int ct = 0; ct < 8; ++ct) bv2[ct] = b2[ct * 16 + l16];

#pragma unroll
    for (int rt = 0; rt < 2; ++rt) {
#pragma unroll
        for (int r = 0; r < 4; ++r) {
            int row = row0 + rt * 16 + quad * 4 + r;
            if (row >= N_NODES) continue;
#pragma unroll
            for (int ct = 0; ct < 8; ++ct) {
                outf[(size_t)row * D + ct * 16 + l16] = acc2[rt][ct][r] + bv2[ct];
            }
        }
    }
}

extern "C" void kernel_launch(void* const* d_in, const int* in_sizes, int n_in,
                              void* d_out, int out_size, void* d_ws, size_t ws_size,
                              hipStream_t stream) {
    const int* indices = (const int*)d_in[0];      // [2, E]
    const float* values = (const float*)d_in[1];   // [E]
    const float* features = (const float*)d_in[2]; // [N, 128]
    const float* W1 = (const float*)d_in[3];
    const float* b1 = (const float*)d_in[4];
    const float* W2 = (const float*)d_in[5];
    const float* b2 = (const float*)d_in[6];

    const int* row = indices;
    const int* col = indices + N_EDGES;

    // ws (ints): coarseCount[CB*16] pad | rowRange[N] int2 | scev[CB*CCAP] int2 |
    //            Xb[N*64] u32 | W1t/W2t u16     total ~40.5 MB
    int* wsI = (int*)d_ws;
    int* coarseCount = wsI;                        // CB*16 = 1568 ints (1/line)
    int2* rowRange = (int2*)(wsI + 1600);          // 800 KB
    int2* scev = (int2*)(wsI + 1600 + 2 * N_NODES);  // 14.05 MB
    u32* Xb = (u32*)(wsI + 1600 + 2 * N_NODES + 2 * CB * CCAP);  // 25.6 MB, 16B-aligned
    u16* W1t = (u16*)(Xb + (size_t)N_NODES * 64);
    u16* W2t = W1t + 16384;

    // d_out: binned[CB*CCAP] int2 (14.05 MB, dead after sortk) lower part;
    // featb (bf16 features, 25.6 MB, dead after spmm) upper half;
    // gemm_fused overwrites everything with outf.
    int2* binned = (int2*)d_out;
    u32* featb = (u32*)((char*)d_out + (size_t)N_NODES * D * 2);
    float* outf = (float*)d_out;

    hipMemsetAsync(coarseCount, 0, CB * 16 * sizeof(int), stream);

    prep<<<BIN_BLKS + CF_BLKS + CW_BLKS, 256, 0, stream>>>(
        features, featb, W1, W2, W1t, W2t, row, col, values, coarseCount, binned);

    sortk<<<CB, 1024, 0, stream>>>(binned, coarseCount, rowRange, scev);

    spmm_bf16<<<(N_NODES * 64 + 255) / 256, 256, 0, stream>>>(scev, rowRange, featb, Xb);

    gemm_fused<<<(N_NODES + 127) / 128, 256, 0, stream>>>(
        (const u16*)Xb, W1t, b1, W2t, b2, outf);
}